// Round 6
// baseline (830.786 us; speedup 1.0000x reference)
//
#include <hip/hip_runtime.h>
#include <cstdint>
#include <cstddef>

// Problem constants
#define NBN   200
#define NS    128
#define ND    1024
#define NDI   2048
#define NST   32
#define NROWS (NBN * NS)          // 25600

typedef __attribute__((ext_vector_type(8))) short bf16x8;   // 8 bf16 = 4 VGPRs
typedef __attribute__((ext_vector_type(4))) float f32x4;

__device__ __forceinline__ unsigned short f2bf(float f) {
    unsigned int u = __float_as_uint(f);
    u += 0x7fffu + ((u >> 16) & 1u);          // round-to-nearest-even
    return (unsigned short)(u >> 16);
}
__device__ __forceinline__ float bf2f(unsigned short h) {
    return __uint_as_float(((unsigned int)h) << 16);
}

// async global->LDS, 16B per lane. LDS dest = wave-uniform base + lane*16.
__device__ __forceinline__ void gl_lds16(const void* g, void* l) {
    typedef __attribute__((address_space(1))) const unsigned int* gp_t;
    typedef __attribute__((address_space(3))) unsigned int* lp_t;
    __builtin_amdgcn_global_load_lds((gp_t)(uintptr_t)g,
                                     (lp_t)(unsigned int)(uintptr_t)l, 16, 0, 0);
}

// ---------------- weight prep: f32 -> bf16 ----------------
__global__ __launch_bounds__(256) void cvt_kernel(const float* __restrict__ src,
                                                  unsigned short* __restrict__ dst, int n) {
    int i = blockIdx.x * 256 + threadIdx.x;
    if (i < n) dst[i] = f2bf(src[i]);
}

// x_proj_W f32 [65,2048] -> padded bf16 [80,2048] (pad rows zero)
__global__ __launch_bounds__(256) void padwx_kernel(const float* __restrict__ src,
                                                    unsigned short* __restrict__ dst) {
    int i = blockIdx.x * 256 + threadIdx.x;   // 80*2048
    int r = i >> 11;
    dst[i] = (r < 65) ? f2bf(src[i]) : (unsigned short)0;
}

// ---------------- LayerNorm: x[row,1024] f32 -> xn bf16 ----------------
__global__ __launch_bounds__(256) void ln_kernel(const float* __restrict__ x,
                                                 const float* __restrict__ gw,
                                                 const float* __restrict__ gb,
                                                 unsigned short* __restrict__ xn) {
    __shared__ float ss[4], ss2[4];
    size_t row = blockIdx.x;
    int tid = threadIdx.x;
    const float4* px = (const float4*)(x + row * ND);
    float4 v = px[tid];
    float s  = v.x + v.y + v.z + v.w;
    float s2 = fmaf(v.x, v.x, fmaf(v.y, v.y, fmaf(v.z, v.z, v.w * v.w)));
    #pragma unroll
    for (int off = 32; off > 0; off >>= 1) {
        s  += __shfl_down(s,  off, 64);
        s2 += __shfl_down(s2, off, 64);
    }
    if ((tid & 63) == 0) { ss[tid >> 6] = s; ss2[tid >> 6] = s2; }
    __syncthreads();
    float tot  = ss[0] + ss[1] + ss[2] + ss[3];
    float tot2 = ss2[0] + ss2[1] + ss2[2] + ss2[3];
    float mu   = tot * (1.f / ND);
    float var  = fmaf(tot2, 1.f / ND, -mu * mu);
    float rstd = rsqrtf(var + 1e-5f);
    float4 wv = ((const float4*)gw)[tid];
    float4 bv = ((const float4*)gb)[tid];
    ushort4 o;
    o.x = f2bf(fmaf((v.x - mu) * rstd, wv.x, bv.x));
    o.y = f2bf(fmaf((v.y - mu) * rstd, wv.y, bv.y));
    o.z = f2bf(fmaf((v.z - mu) * rstd, wv.z, bv.z));
    o.w = f2bf(fmaf((v.w - mu) * rstd, wv.w, bv.w));
    ((ushort4*)(xn + row * ND))[tid] = o;
}

// ================= 256x256 8-phase pipelined MFMA GEMM =================
// C[M,N] = A[M,K] @ B[N,K]^T, bf16 in, f32 acc.
// EPI 1: f32 (acc+resid) nontemporal store.
// EPI 2: fused mamba epilogue: x-half tiles (n0<2048) -> causal conv(4)+silu
//        via wave-private LDS [c][t], store bf16 xact; z-half -> silu, store
//        compact bf16 zs (regular stores: zs is re-read by ssd, keep in LLC).

#define BARRIER __builtin_amdgcn_s_barrier()
#define LGKM0  asm volatile("s_waitcnt lgkmcnt(0)" ::: "memory")
#define VMCNT6 asm volatile("s_waitcnt vmcnt(6)" ::: "memory")
#define VMCNT0 asm volatile("s_waitcnt vmcnt(0)" ::: "memory")
#define NOWAIT ((void)0)
#define PRIO1  __builtin_amdgcn_s_setprio(1)
#define PRIO0  __builtin_amdgcn_s_setprio(0)

#define STG_A(t, kp) {                                                        \
    gl_lds16(gA0 + (size_t)(t) * 64 + (kp) * 32,                              \
             lA + (((t) & 1) << 15) + ((kp) << 14));                          \
    gl_lds16(gA1 + (size_t)(t) * 64 + (kp) * 32,                              \
             lA + (((t) & 1) << 15) + ((kp) << 14) + 8192); }
#define STG_B(t, kp) {                                                        \
    gl_lds16(gB0 + (size_t)(t) * 64 + (kp) * 32,                              \
             lB + (((t) & 1) << 15) + ((kp) << 14));                          \
    gl_lds16(gB1 + (size_t)(t) * 64 + (kp) * 32,                              \
             lB + (((t) & 1) << 15) + ((kp) << 14) + 8192); }

#define RD_A(dst, mh, kp) { _Pragma("unroll")                                 \
    for (int mi = 0; mi < 4; ++mi)                                            \
        dst[mi] = *(const bf16x8*)(aRd + bo + (kp) * 16384 + (mh) * 4096 + mi * 1024); }
#define RD_B(dst, kp) { _Pragma("unroll")                                     \
    for (int ni = 0; ni < 4; ++ni)                                            \
        dst[ni] = *(const bf16x8*)(bRd + bo + (kp) * 16384 + ni * 1024); }

#define MM(mh, AV, BV) { _Pragma("unroll")                                    \
    for (int mi = 0; mi < 4; ++mi) { _Pragma("unroll")                        \
        for (int ni = 0; ni < 4; ++ni)                                        \
            acc[(mh) * 4 + mi][ni] = __builtin_amdgcn_mfma_f32_16x16x32_bf16( \
                AV[mi], BV[ni], acc[(mh) * 4 + mi][ni], 0, 0, 0); } }

#define TILE(t, DO_AP1, DO_T2, W) {                                           \
    const int bo = ((t) & 1) << 15;                                           \
    RD_A(aK0, 0, 0); RD_B(bK0, 0);                                            \
    if (DO_AP1) STG_A((t) + 1, 1);                                            \
    BARRIER; LGKM0; PRIO1; MM(0, aK0, bK0); PRIO0; BARRIER;                   \
    RD_A(aK1, 0, 1); RD_B(bK1, 1);                                            \
    if (DO_T2) STG_B((t) + 2, 0);                                             \
    BARRIER; LGKM0; PRIO1; MM(0, aK1, bK1); PRIO0; BARRIER;                   \
    RD_A(aK0, 1, 0);                                                          \
    if (DO_T2) STG_B((t) + 2, 1);                                             \
    BARRIER; LGKM0; PRIO1; MM(1, aK0, bK0); PRIO0; BARRIER;                   \
    RD_A(aK1, 1, 1);                                                          \
    if (DO_T2) STG_A((t) + 2, 0);                                             \
    BARRIER; LGKM0; PRIO1; MM(1, aK1, bK1); PRIO0;                            \
    W;                                                                        \
    BARRIER; }

template <int K, int EPI>
__global__ __launch_bounds__(512, 2)
void gemm256(const unsigned short* __restrict__ A,
             const unsigned short* __restrict__ B,
             int N, void* __restrict__ outp, const float* __restrict__ resid,
             const float* __restrict__ cw, const float* __restrict__ cb,
             unsigned short* __restrict__ out2) {
    constexpr int NT = K / 64;
    static_assert(NT >= 3, "need >=3 K-tiles");
    __shared__ __align__(16) char smem[131072];

    const int tid  = threadIdx.x;
    const int lane = tid & 63;
    const int wid  = tid >> 6;
    const int lrow = lane & 15;
    const int kq   = lane >> 4;
    const int wmi  = wid >> 2;
    const int wni  = wid & 3;

    // T1: bijective XCD swizzle, bn-minor within each XCD chunk
    const int gx  = gridDim.x;
    const int gy  = gridDim.y;
    const int nwg = gx * gy;
    const int lin = blockIdx.y * gx + blockIdx.x;
    const int id2 = (lin & 7) * (nwg >> 3) + (lin >> 3);
    const int bn  = id2 % gy;
    const int bm  = id2 / gy;

    const size_t m0 = (size_t)bm * 256;
    const size_t n0 = (size_t)bn * 256;

    const int fr = (lrow >> 1) & 3;
    const char* aRd = smem +          (wmi * 128 + lrow) * 64 + ((kq ^ fr) << 4);
    const char* bRd = smem + 65536 + (wni * 64  + lrow) * 64 + ((kq ^ fr) << 4);

    const int srow = wid * 16 + (lane >> 2);
    const int scol = (((lane & 3) ^ ((lane >> 3) & 3)) << 3);
    const unsigned short* gA0 = A + (m0 + srow) * K + scol;
    const unsigned short* gA1 = A + (m0 + 128 + srow) * K + scol;
    const unsigned short* gB0 = B + (n0 + srow) * K + scol;
    const unsigned short* gB1 = B + (n0 + 128 + srow) * K + scol;
    char* lA = smem + wid * 1024;
    char* lB = smem + 65536 + wid * 1024;

    f32x4 acc[8][4];
    #pragma unroll
    for (int i = 0; i < 8; ++i)
        #pragma unroll
        for (int j = 0; j < 4; ++j) acc[i][j] = (f32x4){0.f, 0.f, 0.f, 0.f};

    bf16x8 aK0[4], aK1[4], bK0[4], bK1[4];

    STG_B(0, 0); STG_B(0, 1); STG_A(0, 0); STG_A(0, 1);
    STG_B(1, 0); STG_B(1, 1); STG_A(1, 0);
    VMCNT6;
    BARRIER;

    int t = 0;
    #pragma unroll 2
    for (; t < NT - 2; ++t) { TILE(t, 1, 1, VMCNT6); }
    TILE((NT - 2), 1, 0, VMCNT0);
    TILE((NT - 1), 0, 0, NOWAIT);

    if (EPI == 1) {
        #pragma unroll
        for (int mi = 0; mi < 8; ++mi)
            #pragma unroll
            for (int ni = 0; ni < 4; ++ni)
                #pragma unroll
                for (int r = 0; r < 4; ++r) {
                    size_t row = m0 + wmi * 128 + mi * 16 + kq * 4 + r;
                    size_t col = n0 + wni * 64 + ni * 16 + lrow;
                    size_t idx = row * (size_t)N + col;
                    float v = acc[mi][ni][r] + __builtin_nontemporal_load(&resid[idx]);
                    __builtin_nontemporal_store(v, &((float*)outp)[idx]);
                }
    } else {
        // EPI == 2: fused mamba epilogue
        BARRIER;                                   // all waves done with smem
        if (n0 < 2048) {
            // ---- causal conv(4) + silu, wave-private LDS [c][t] bf16 swz ----
            char* wb = smem + wid * 16384;
            #pragma unroll
            for (int mi = 0; mi < 8; ++mi)
                #pragma unroll
                for (int ni = 0; ni < 4; ++ni) {
                    int cl = ni * 16 + lrow;       // local channel row 0..63
                    int slot = mi * 2 + (kq >> 1); // t-slot 0..15
                    ushort4 pk;
                    pk.x = f2bf(acc[mi][ni][0]); pk.y = f2bf(acc[mi][ni][1]);
                    pk.z = f2bf(acc[mi][ni][2]); pk.w = f2bf(acc[mi][ni][3]);
                    *(ushort4*)(wb + cl * 256 +
                                (((slot ^ lrow) << 4) | ((kq & 1) << 3))) = pk;
                }
            LGKM0;
            __builtin_amdgcn_sched_barrier(0);
            const int ch = (int)n0 + wni * 64 + lane;   // global channel
            float4 wv = ((const float4*)cw)[ch];
            float bias = cb[ch];
            float x0 = 0.f, x1 = 0.f, x2 = 0.f;
            unsigned short* po = (unsigned short*)outp + (m0 + wmi * 128) * NDI + ch;
            const char* rb = wb + lane * 256;
            const int cx = lane & 15;
            for (int s = 0; s < 16; ++s) {
                bf16x8 v = *(const bf16x8*)(rb + ((s ^ cx) << 4));
                #pragma unroll
                for (int j = 0; j < 8; ++j) {
                    float x3 = bf2f((unsigned short)v[j]);
                    float vv = fmaf(x3, wv.w, fmaf(x2, wv.z,
                               fmaf(x1, wv.y, fmaf(x0, wv.x, bias))));
                    float sg = vv * __builtin_amdgcn_rcpf(1.f + __expf(-vv));
                    po[(size_t)(s * 8 + j) * NDI] = f2bf(sg);
                    x0 = x1; x1 = x2; x2 = x3;
                }
            }
        } else {
            // ---- z-half: zs = silu(acc) compact bf16 (regular stores) ----
            #pragma unroll
            for (int mi = 0; mi < 8; ++mi)
                #pragma unroll
                for (int ni = 0; ni < 4; ++ni)
                    #pragma unroll
                    for (int r = 0; r < 4; ++r) {
                        size_t row = m0 + wmi * 128 + mi * 16 + kq * 4 + r;
                        size_t col = (n0 - 2048) + wni * 64 + ni * 16 + lrow;
                        float v = acc[mi][ni][r];
                        float sg = v * __builtin_amdgcn_rcpf(1.f + __expf(-v));
                        out2[row * 2048 + col] = f2bf(sg);
                    }
        }
    }
}

// ---------------- GEMM2: x_ssm[25600,80] = x_act[25600,2048] @ Wx[80,2048]^T ----------------
__global__ __launch_bounds__(256, 2)
void gemm2_kernel(const unsigned short* __restrict__ A,
                  const unsigned short* __restrict__ B,
                  float* __restrict__ out) {
    __shared__ __align__(16) unsigned short As[64 * 32];
    __shared__ __align__(16) unsigned short Bs[80 * 32];
    const int tid  = threadIdx.x;
    const int bm   = blockIdx.x;
    const int wid  = tid >> 6;
    const int lane = tid & 63;
    const int lrow = lane & 15;
    const int kq   = lane >> 4;

    f32x4 acc[5];
    #pragma unroll
    for (int i = 0; i < 5; i++) acc[i] = (f32x4){0.f, 0.f, 0.f, 0.f};

    const int r1 = tid >> 2;
    const int c8 = (tid & 3) << 3;
    const unsigned short* gA1 = A + ((size_t)bm * 64 + r1) * NDI + c8;
    const unsigned short* gB1 = B + (size_t)r1 * NDI + c8;
    const unsigned short* gB2 = B + (size_t)(64 + r1) * NDI + c8;
    char* lA1 = (char*)As + wid * 1024;
    char* lB1 = (char*)Bs + wid * 1024;
    char* lB2 = (char*)Bs + 4096;

    for (int kt = 0; kt < NDI; kt += 32) {
        __syncthreads();
        gl_lds16(gA1, lA1);
        gl_lds16(gB1, lB1);
        if (tid < 64) gl_lds16(gB2, lB2);
        gA1 += 32; gB1 += 32; gB2 += 32;
        __syncthreads();
        bf16x8 af = *(const bf16x8*)&As[(wid * 16 + lrow) * 32 + kq * 8];
        #pragma unroll
        for (int ni = 0; ni < 5; ni++) {
            bf16x8 bfr = *(const bf16x8*)&Bs[(ni * 16 + lrow) * 32 + kq * 8];
            acc[ni] = __builtin_amdgcn_mfma_f32_16x16x32_bf16(af, bfr, acc[ni], 0, 0, 0);
        }
    }
    #pragma unroll
    for (int ni = 0; ni < 5; ni++)
        #pragma unroll
        for (int r = 0; r < 4; r++) {
            size_t row = (size_t)bm * 64 + wid * 16 + kq * 4 + r;
            int col = ni * 16 + lrow;
            out[row * 80 + col] = acc[ni][r];
        }
}

// ================= SSD chunked selective scan (pipelined) =================
// Per block: (b, 256-d slice). 4 chunks of T=32 steps, h0 carried in LDS.
// y[t,d] = Einv[t,d]*( C@h0 + Gmask@P )[t,d],  P[s,d]=xa*exp(L'[s,d]),
// h0' = Einv[31,d]*(h0 + B^T@P).  G[t,s]=sum_n C[t,n]B[s,n] shared over d.
// Pipelining: chunk c+1's global loads (xssm stage, eb, xa) issued at top of
// body c into regs; drained by the mid barrier after ~2k cyc of compute.
// Stage LDS single-buffered: all stage READS are pre-barrier (frags hoisted),
// stage WRITES for c+1 are post-barrier. sP/sE/sH are wave-local rows.
// P/E: delta (indep ILP) -> 32-add prefix -> exp; Einv = rcp(exp(L)).
// C@h0 and B^T@P MFMAs hoisted pre-barrier (wave-local operands); only
// G@P + epilogue + h-update post-barrier. 2 barriers/chunk (was 3).
#define SSD_PF(c, XN) {                                                       \
    const float* src = xssm + ((size_t)b * 128 + ((c) + 1) * 32) * 80;        \
    _Pragma("unroll")                                                         \
    for (int k = 0; k < 10; ++k) fr[k] = src[tid + k * 256];                  \
    ebr = (tid < 32) ? es * eb[b * 128 + ((c) + 1) * 32 + tid] : 0.f;         \
    const unsigned short* pxa =                                               \
        xact_g + ((size_t)b * 128 + ((c) + 1) * 32) * 2048 + d0 + tid;        \
    _Pragma("unroll")                                                         \
    for (int t = 0; t < 32; ++t) XN[t] = pxa[(size_t)t * 2048];               \
}

#define SSD_WSTG() {                                                          \
    _Pragma("unroll")                                                         \
    for (int k = 0; k < 10; ++k) {                                            \
        int i = tid + k * 256;                                                \
        int t = i / 80, col = i - t * 80;                                     \
        float v = fr[k];                                                      \
        if (col == 0) sDR[t] = v;                                             \
        else if (col < 33) { unsigned short bv = f2bf(v);                     \
            sB[t][col - 1] = bv; sBt[col - 1][t] = bv; }                      \
        else if (col < 65) sC[t][col - 33] = f2bf(v);                         \
    }                                                                         \
    if (tid < 32) sDE[tid] = ebr;                                             \
}

#define SSD_BODY(c, XC, XN, DOPF) {                                           \
    if (DOPF) SSD_PF(c, XN)                       /* c+1 loads in flight */   \
    /* ---- G = tril(C B^T) (stage reads, pre-barrier) ---- */                \
    {                                                                         \
        int gmi = wid >> 1, gni = wid & 1;                                    \
        bf16x8 af = *(const bf16x8*)&sC[gmi * 16 + lrow][kq * 8];             \
        bf16x8 bv = *(const bf16x8*)&sB[gni * 16 + lrow][kq * 8];             \
        f32x4 z4 = (f32x4){0.f, 0.f, 0.f, 0.f};                               \
        f32x4 g = __builtin_amdgcn_mfma_f32_16x16x32_bf16(af, bv, z4, 0,0,0); \
        _Pragma("unroll")                                                     \
        for (int r = 0; r < 4; ++r) {                                         \
            int t = gmi * 16 + kq * 4 + r, s = gni * 16 + lrow;               \
            float val = (s <= t) ? g[r] : 0.f;                                \
            *(unsigned short*)((char*)sG + t * 64 +                           \
                ((((s >> 3) ^ (t & 3)) << 4) | ((s & 7) << 1))) = f2bf(val);  \
        }                                                                     \
    }                                                                         \
    /* ---- P/E: delta (ILP) -> prefix -> exp ---- */                         \
    {                                                                         \
        float L[32];                                                          \
        _Pragma("unroll")                                                     \
        for (int t = 0; t < 32; ++t) {                                        \
            float raw = fmaf(sDR[t], w, bb);                                  \
            float sp  = (raw > 20.f) ? raw : __logf(1.f + __expf(raw));       \
            L[t] = fmaxf(sp + sDE[t], 1e-4f);                                 \
        }                                                                     \
        _Pragma("unroll")                                                     \
        for (int t = 1; t < 32; ++t) L[t] += L[t - 1];                        \
        _Pragma("unroll")                                                     \
        for (int t8 = 0; t8 < 4; ++t8) {                                      \
            bf16x8 pv;                                                        \
            _Pragma("unroll")                                                 \
            for (int j = 0; j < 8; ++j) {                                     \
                int t = t8 * 8 + j;                                           \
                float E = __expf(L[t]);                                       \
                pv[j] = (short)f2bf(bf2f(XC[t]) * E);                         \
                *(float*)((char*)sE + tid * 128 +                             \
                    ((((t >> 2) ^ (tid & 7)) << 4) | ((t & 3) << 2))) =       \
                    __builtin_amdgcn_rcpf(E);                                 \
            }                                                                 \
            *(bf16x8*)((char*)sP + tid * 64 + (((t8 ^ (tid & 3)) << 4))) = pv;\
        }                                                                     \
    }                                                                         \
    /* ---- hoisted wave-local frags + pre-barrier MFMAs ---- */              \
    f32x4 acc[2][4], racc[2][4];                                              \
    bf16x8 gfrag[2], pfrag[4];                                                \
    {                                                                         \
        bf16x8 cfrag[2], btfrag[2], hfrag[4];                                 \
        _Pragma("unroll")                                                     \
        for (int mi = 0; mi < 2; ++mi) {                                      \
            int tr = mi * 16 + lrow;                                          \
            cfrag[mi]  = *(const bf16x8*)&sC[tr][kq * 8];                     \
            btfrag[mi] = *(const bf16x8*)&sBt[tr][kq * 8];                    \
        }                                                                     \
        _Pragma("unroll")                                                     \
        for (int ni = 0; ni < 4; ++ni) {                                      \
            int dc = wd0 + ni * 16 + lrow;                                    \
            hfrag[ni] = *(const bf16x8*)&sH[dc][kq * 8];                      \
            pfrag[ni] = *(const bf16x8*)((const char*)sP + dc * 64 +          \
                                         (((kq ^ (dc & 3)) << 4)));           \
        }                                                                     \
        _Pragma("unroll")                                                     \
        for (int mi = 0; mi < 2; ++mi)                                        \
            _Pragma("unroll")                                                 \
            for (int ni = 0; ni < 4; ++ni) {                                  \
                f32x4 z4 = (f32x4){0.f, 0.f, 0.f, 0.f};                       \
                acc[mi][ni] = __builtin_amdgcn_mfma_f32_16x16x32_bf16(        \
                    cfrag[mi], hfrag[ni], z4, 0, 0, 0);                       \
                racc[mi][ni] = __builtin_amdgcn_mfma_f32_16x16x32_bf16(       \
                    btfrag[mi], pfrag[ni], z4, 0, 0, 0);                      \
            }                                                                 \
    }                                                                         \
    __syncthreads();                              /* sG visible; PF drained */\
    if (DOPF) SSD_WSTG()                          /* stage c+1 (post-reads) */\
    _Pragma("unroll")                                                         \
    for (int mi = 0; mi < 2; ++mi) {                                          \
        int tr = mi * 16 + lrow;                                              \
        gfrag[mi] = *(const bf16x8*)((const char*)sG + tr * 64 +              \
                                     (((kq ^ (tr & 3)) << 4)));               \
    }                                                                         \
    _Pragma("unroll")                                                         \
    for (int mi = 0; mi < 2; ++mi)                                            \
        _Pragma("unroll")                                                     \
        for (int ni = 0; ni < 4; ++ni)                                        \
            acc[mi][ni] = __builtin_amdgcn_mfma_f32_16x16x32_bf16(            \
                gfrag[mi], pfrag[ni], acc[mi][ni], 0, 0, 0);                  \
    /* ---- epilogue: g = Einv*acc * zs ---- */                               \
    _Pragma("unroll")                                                         \
    for (int mi = 0; mi < 2; ++mi)                                            \
        _Pragma("unroll")                                                     \
        for (int ni = 0; ni < 4; ++ni) {                                      \
            int dc = wd0 + ni * 16 + lrow;                                    \
            f32x4 ev = *(const f32x4*)((const char*)sE + dc * 128 +           \
                                       ((((mi * 4 + kq) ^ (dc & 7)) << 4)));  \
            size_t rowg = (size_t)b * 128 + (c) * 32 + mi * 16 + kq * 4;      \
            _Pragma("unroll")                                                 \
            for (int r = 0; r < 4; ++r) {                                     \
                size_t gi = (rowg + r) * 2048 + d0 + dc;                      \
                float y  = acc[mi][ni][r] * ev[r];                            \
                xact_g[gi] = f2bf(y * bf2f(zs[gi]));                          \
            }                                                                 \
        }                                                                     \
    /* ---- h0' = Einv[31]*(h0 + R), wave-local rows ---- */                  \
    _Pragma("unroll")                                                         \
    for (int ni = 0; ni < 4; ++ni) {                                          \
        int dc = wd0 + ni * 16 + lrow;                                        \
        float e31 = *(const float*)((const char*)sE + dc * 128 +              \
                                    (((7 ^ (dc & 7)) << 4) | 12));            \
        _Pragma("unroll")                                                     \
        for (int mi = 0; mi < 2; ++mi)                                        \
            _Pragma("unroll")                                                 \
            for (int r = 0; r < 4; ++r) {                                     \
                int n = mi * 16 + kq * 4 + r;                                 \
                float h = bf2f(sH[dc][n]) + racc[mi][ni][r];                  \
                sH[dc][n] = f2bf(e31 * h);                                    \
            }                                                                 \
    }                                                                         \
    __syncthreads();                                                          \
}

__global__ __launch_bounds__(256, 2)
void ssd_kernel(const float* __restrict__ xssm,          // [25600,80]: [dr | B(32) | C(32) | pad]
                unsigned short* xact_g,                   // in: x_act, out: g (bf16, in-place)
                const unsigned short* __restrict__ zs,    // silu(z) bf16 [25600,2048]
                const float* __restrict__ dtW,
                const float* __restrict__ dtb,
                const float* __restrict__ eb,             // [25600] f32
                const float* __restrict__ es_p) {
    __shared__ float sDR[32], sDE[32];
    __shared__ __align__(16) unsigned short sC[32][32];    // [t][n]
    __shared__ __align__(16) unsigned short sB[32][32];    // [s][n]
    __shared__ __align__(16) unsigned short sBt[32][32];   // [n][s]
    __shared__ __align__(16) unsigned short sG[32][32];    // [t][s] swz
    __shared__ __align__(16) unsigned short sP[256][32];   // [dloc][s] swz (wave-local)
    __shared__ __align__(16) float          sE[256][32];   // [dloc][t] swz, Einv
    __shared__ __align__(16) unsigned short sH[256][32];   // [dloc][n] h0 bf16

    const int tid  = threadIdx.x;
    const int b    = blockIdx.y;
    const int d0   = blockIdx.x * 256;
    const int lane = tid & 63;
    const int wid  = tid >> 6;
    const int lrow = lane & 15;
    const int kq   = lane >> 4;
    const int wd0  = wid * 64;

    const float w  = dtW[d0 + tid];
    const float bb = dtb[d0 + tid];
    const float es = es_p[0];

    // h0 = 0
    for (int i = tid; i < 256 * 32; i += 256) ((unsigned short*)sH)[i] = 0;

    float fr[10]; float ebr;
    unsigned short xaA[32], xaB[32];

    // prologue: chunk 0 loads -> stage + xaA
    {
        const float* src = xssm + ((size_t)b * 128) * 80;
        #pragma unroll
        for (int k = 0; k < 10; ++k) fr[k] = src[tid + k * 256];
        ebr = (tid < 32) ? es * eb[b * 128 + tid] : 0.f;
        const unsigned short* pxa = xact_g + ((size_t)b * 128) * 2048 + d0 + tid;
        #pragma unroll
        for (int t = 0; t < 32; ++t) xaA[t] = pxa[(size_t)t * 2048];
        SSD_WSTG()
    }
    __syncthreads();

    SSD_BODY(0, xaA, xaB, 1)
    SSD_BODY(1, xaB, xaA, 1)
    SSD_BODY(2, xaA, xaB, 1)
    SSD_BODY(3, xaB, xaA, 0)
}

// ---------------- launch ----------------
extern "C" void kernel_launch(void* const* d_in, const int* in_sizes, int n_in,
                              void* d_out, int out_size, void* d_ws, size_t ws_size,
                              hipStream_t stream) {
    const float* x   = (const float*)d_in[0];
    const float* eb  = (const float*)d_in[1];
    const float* nw  = (const float*)d_in[2];
    const float* nb  = (const float*)d_in[3];
    const float* Wi  = (const float*)d_in[4];
    const float* cw  = (const float*)d_in[5];
    const float* cb  = (const float*)d_in[6];
    const float* Wx  = (const float*)d_in[7];
    const float* dtW = (const float*)d_in[8];
    const float* dtb = (const float*)d_in[9];
    const float* Wo  = (const float*)d_in[10];
    const float* es  = (const float*)d_in[11];
    float* out = (float*)d_out;                     // FLOAT32 output

    // workspace layout (bytes, 256-aligned)
    char* ws = (char*)d_ws;
    unsigned short* wi_b   = (unsigned short*)(ws + 0);            //   8,388,608
    unsigned short* wo_b   = (unsigned short*)(ws + 8388608);      //   4,194,304
    unsigned short* wx_b   = (unsigned short*)(ws + 12582912);     //     327,680
    unsigned short* zs_b   = (unsigned short*)(ws + 12910592);     // 104,857,600 silu(z)
    unsigned short* xn_b   = (unsigned short*)(ws + 117768192);    //  52,428,800
    unsigned short* xact_b = (unsigned short*)(ws + 170196992);    // 104,857,600
    float*          xssm   = (float*)(ws + 275054592);             //   8,192,000 -> 283,246,592
    if (ws_size < (size_t)283246592) return;

    // 1. weights -> bf16
    cvt_kernel<<<(2 * NDI * ND + 255) / 256, 256, 0, stream>>>(Wi, wi_b, 2 * NDI * ND);
    cvt_kernel<<<(ND * NDI + 255) / 256, 256, 0, stream>>>(Wo, wo_b, ND * NDI);
    padwx_kernel<<<(80 * NDI) / 256, 256, 0, stream>>>(Wx, wx_b);

    // 2. LayerNorm -> xn (bf16)
    ln_kernel<<<NROWS, 256, 0, stream>>>(x, nw, nb, xn_b);

    // 3. GEMM1 fused: x_act = silu(conv(xn @ Wi^T[:,0:2048])), zs = silu(z-half)
    gemm256<ND, 2><<<dim3(NROWS / 256, (2 * NDI) / 256), 512, 0, stream>>>(
        xn_b, wi_b, 2 * NDI, xact_b, nullptr, cw, cb, zs_b);

    // 4. GEMM2: x_ssm = x_act @ Wx^T  [25600,80] f32
    gemm2_kernel<<<NROWS / 64, 256, 0, stream>>>(xact_b, wx_b, xssm);

    // 5. SSD chunked scan + gating (g overwrites x_act)
    ssd_kernel<<<dim3(NDI / 256, NBN), 256, 0, stream>>>(xssm, xact_b, zs_b, dtW, dtb, eb, es);

    // 6. GEMM3: out = g @ Wo^T + residual  (f32 nontemporal store)
    gemm256<NDI, 1><<<dim3(NROWS / 256, ND / 256), 512, 0, stream>>>(
        xact_b, wo_b, ND, out, x, nullptr, nullptr, nullptr);
}